// Round 4
// baseline (59.039 us; speedup 1.0000x reference)
//
#include <hip/hip_runtime.h>

#define TWO_PI_F 6.283185307179586f

// Problem constants (from setup_inputs)
#define C_O   512
#define C_CIN 512
#define C_K   16
#define C_KS  7
#define C_NI  16
#define C_NO  16

#define OUT0_SIZE (C_O * C_NI * C_CIN * C_NO)   // 67,108,864
#define OUT1_SIZE (C_O * C_NO * C_KS * C_KS)    // 401,408

// LDS row stride: 16 data + 1 wrap-dup + 1 pad = 18 floats. 18c mod 32 spreads
// 16 consecutive rows over 16 distinct banks; 8B-aligned for float2 staging.
#define SW_STRIDE 18

#define BILIN_PER_BLOCK 784   // OUT1_SIZE / 512 exactly

typedef float f32x4 __attribute__((ext_vector_type(4)));

// ---------------------------------------------------------------------------
// One block per o (512 blocks, 1024 threads, 2 blocks/CU -> one generation).
// Phase 1: stage weight_H[o,:,:] (32 KB) into LDS once.
// Phase 2: stream 512 KB contiguous out0[o] via 32 nt f32x4 stores/thread.
// Phase 3 (tail): 784 bilinear out1 elements per block, overlapping store drain.
// ---------------------------------------------------------------------------
__global__ __launch_bounds__(1024, 8) void fused_kernel(
    const float* __restrict__ in_H,
    const float* __restrict__ out_H,
    const float* __restrict__ weight_H,
    const float* __restrict__ weight,
    const float* __restrict__ grid_Rn,
    const float* __restrict__ mask,
    float* __restrict__ out0,
    float* __restrict__ out1)
{
    __shared__ float s_w[C_CIN * SW_STRIDE];   // 36,864 B
    __shared__ float s_t[C_NI * C_NO];         // 256 t-coords

    const int tid = threadIdx.x;
    const int o   = blockIdx.x;

    // t coordinate per (ni, no)
    if (tid < 256) {
        int ni = tid >> 4;
        int no = tid & 15;
        float x = in_H[ni] - out_H[no];
        float r = fmodf(x, TWO_PI_F);
        if (r < 0.0f) r += TWO_PI_F;
        s_t[tid] = r * (16.0f / TWO_PI_F);
    }

    // Stage weight_H[o,:,:] (512 rows x 16 floats = 32 KB), stride 18 + wrap dup
    const float4* wsrc = reinterpret_cast<const float4*>(weight_H) + (size_t)o * 2048;
#pragma unroll
    for (int j = 0; j < 2; ++j) {
        int f = j * 1024 + tid;                // float4 index: c = f/4, part = f%4
        float4 v = wsrc[f];
        int c    = f >> 2;
        int part = f & 3;
        float* row = &s_w[c * SW_STRIDE + part * 4];
        reinterpret_cast<float2*>(row)[0] = make_float2(v.x, v.y);
        reinterpret_cast<float2*>(row)[1] = make_float2(v.z, v.w);
        if (part == 0) s_w[c * SW_STRIDE + 16] = v.x;   // wrap duplicate
    }
    __syncthreads();

    // This thread covers no = 4*q + e and rows c = crow, crow+256
    const int q    = tid & 3;
    const int crow = tid >> 2;
    const float* wv0 = &s_w[crow * SW_STRIDE];
    const float* wv1 = &s_w[(256 + crow) * SW_STRIDE];
    f32x4* obase = reinterpret_cast<f32x4*>(out0) + ((size_t)o << 15);

#pragma unroll
    for (int ni = 0; ni < C_NI; ++ni) {
        int   i0e[4];
        float fe[4];
#pragma unroll
        for (int e = 0; e < 4; ++e) {
            float tt = s_t[ni * 16 + q * 4 + e];   // quad-uniform LDS broadcast
            float fl = floorf(tt);
            i0e[e] = ((int)fl) & 15;
            fe[e]  = tt - fl;
        }
#pragma unroll
        for (int half = 0; half < 2; ++half) {
            const float* wv = half ? wv1 : wv0;
            f32x4 res;
            res.x = (1.0f - fe[0]) * wv[i0e[0]] + fe[0] * wv[i0e[0] + 1];
            res.y = (1.0f - fe[1]) * wv[i0e[1]] + fe[1] * wv[i0e[1] + 1];
            res.z = (1.0f - fe[2]) * wv[i0e[2]] + fe[2] * wv[i0e[2] + 1];
            res.w = (1.0f - fe[3]) * wv[i0e[3]] + fe[3] * wv[i0e[3] + 1];
            // wave store = contiguous 1 KB; full block streams 512 KB contiguous
            __builtin_nontemporal_store(res, obase + ni * 2048 + half * 1024 + tid);
        }
    }

    // ---- bilinear tail: 784 out1 elements per block, overlaps store drain ----
    if (tid < BILIN_PER_BLOCK) {
        int idx = o * BILIN_PER_BLOCK + tid;
        int pix = idx % 49;                    // ky*7 + kx
        int no  = (idx / 49) & 15;
        int oo  = idx / (49 * 16);

        float gx = grid_Rn[pix * 2 + 0];
        float gy = grid_Rn[pix * 2 + 1];

        float ang = -out_H[no];
        float sn, cs;
        sincosf(ang, &sn, &cs);

        float x = cs * gx - sn * gy;
        float y = sn * gx + cs * gy;

        float X = (x + 1.0f) * 3.0f;           // align_corners map to [0,6]
        float Y = (y + 1.0f) * 3.0f;

        float x0f = floorf(X), y0f = floorf(Y);
        float wx = X - x0f,    wy = Y - y0f;
        int   x0 = (int)x0f,   y0 = (int)y0f;

        const float* img = weight + oo * 49;

        auto gat = [&](int yy, int xx) -> float {
            bool v = (yy >= 0) & (yy < 7) & (xx >= 0) & (xx < 7);
            int yc = min(max(yy, 0), 6);
            int xc = min(max(xx, 0), 6);
            float val = img[yc * 7 + xc];
            return v ? val : 0.0f;
        };

        float r = (1.0f - wy) * (1.0f - wx) * gat(y0,     x0)
                + (1.0f - wy) * wx          * gat(y0,     x0 + 1)
                + wy          * (1.0f - wx) * gat(y0 + 1, x0)
                + wy          * wx          * gat(y0 + 1, x0 + 1);

        out1[idx] = mask[pix] * r;
    }
}

extern "C" void kernel_launch(void* const* d_in, const int* in_sizes, int n_in,
                              void* d_out, int out_size, void* d_ws, size_t ws_size,
                              hipStream_t stream) {
    const float* in_H     = (const float*)d_in[0];
    const float* out_H    = (const float*)d_in[1];
    const float* weight_H = (const float*)d_in[2];
    const float* weight   = (const float*)d_in[3];
    // d_in[4] = grid_H (implicit in uniform-grid formula), unused
    const float* grid_Rn  = (const float*)d_in[5];
    const float* mask     = (const float*)d_in[6];

    float* out0 = (float*)d_out;
    float* out1 = out0 + OUT0_SIZE;

    hipLaunchKernelGGL(fused_kernel, dim3(C_O), dim3(1024), 0, stream,
                       in_H, out_H, weight_H, weight, grid_Rn, mask, out0, out1);
}

// Round 5
// 57.551 us; speedup vs baseline: 1.0258x; 1.0258x over previous
//
#include <hip/hip_runtime.h>

#define TWO_PI_F 6.283185307179586f

// Problem constants (from setup_inputs)
#define C_O   512
#define C_CIN 512
#define C_K   16
#define C_KS  7
#define C_NI  16
#define C_NO  16

#define OUT0_SIZE (C_O * C_NI * C_CIN * C_NO)   // 67,108,864
#define OUT1_SIZE (C_O * C_NO * C_KS * C_KS)    // 401,408

// LDS row stride: 16 data + 1 wrap-dup + 1 pad = 18 floats. 18c mod 32 spreads
// 16 consecutive rows over 16 distinct banks; 8B-aligned for float2 staging.
#define SW_STRIDE 18

#define BILIN_PER_BLOCK 784   // OUT1_SIZE / 512 exactly

typedef float f32x4 __attribute__((ext_vector_type(4)));

// ---------------------------------------------------------------------------
// One block per o (512 blocks, 1024 threads, 2 blocks/CU -> one generation).
// Phase 1: stage weight_H[o,:,:] (32 KB) into LDS once.
// Phase 2: stream 512 KB contiguous out0[o]; ni-loop kept lean (unroll 2) so
//          VGPR stays well under the 64 cap -> no spills, full 32 waves/CU.
// Phase 3 (tail): 784 bilinear out1 elements per block, overlapping drain.
// ---------------------------------------------------------------------------
__global__ __launch_bounds__(1024, 8) void fused_kernel(
    const float* __restrict__ in_H,
    const float* __restrict__ out_H,
    const float* __restrict__ weight_H,
    const float* __restrict__ weight,
    const float* __restrict__ grid_Rn,
    const float* __restrict__ mask,
    float* __restrict__ out0,
    float* __restrict__ out1)
{
    __shared__ float s_w[C_CIN * SW_STRIDE];   // 36,864 B
    __shared__ float s_t[C_NI * C_NO];         // 256 t-coords

    const int tid = threadIdx.x;
    const int o   = blockIdx.x;

    // t coordinate per (ni, no)
    if (tid < 256) {
        int ni = tid >> 4;
        int no = tid & 15;
        float x = in_H[ni] - out_H[no];
        float r = fmodf(x, TWO_PI_F);
        if (r < 0.0f) r += TWO_PI_F;
        s_t[tid] = r * (16.0f / TWO_PI_F);
    }

    // Stage weight_H[o,:,:] (512 rows x 16 floats = 32 KB), stride 18 + wrap dup
    const float4* wsrc = reinterpret_cast<const float4*>(weight_H) + (size_t)o * 2048;
#pragma unroll
    for (int j = 0; j < 2; ++j) {
        int f = j * 1024 + tid;                // float4 index: c = f/4, part = f%4
        float4 v = wsrc[f];
        int c    = f >> 2;
        int part = f & 3;
        float* row = &s_w[c * SW_STRIDE + part * 4];
        reinterpret_cast<float2*>(row)[0] = make_float2(v.x, v.y);
        reinterpret_cast<float2*>(row)[1] = make_float2(v.z, v.w);
        if (part == 0) s_w[c * SW_STRIDE + 16] = v.x;   // wrap duplicate
    }
    __syncthreads();

    // This thread covers no = 4*q + e and rows c = crow, crow+256
    const int q    = tid & 3;
    const int crow = tid >> 2;
    const float* wv0 = &s_w[crow * SW_STRIDE];
    const float* wv1 = &s_w[(256 + crow) * SW_STRIDE];
    f32x4* optr = reinterpret_cast<f32x4*>(out0) + ((size_t)o << 15) + tid;

#pragma unroll 2
    for (int ni = 0; ni < C_NI; ++ni) {
        int   i0e[4];
        float fe[4];
#pragma unroll
        for (int e = 0; e < 4; ++e) {
            float tt = s_t[ni * 16 + q * 4 + e];   // quad-uniform LDS broadcast
            float fl = floorf(tt);
            i0e[e] = ((int)fl) & 15;
            fe[e]  = tt - fl;
        }
        {
            f32x4 res;
            res.x = (1.0f - fe[0]) * wv0[i0e[0]] + fe[0] * wv0[i0e[0] + 1];
            res.y = (1.0f - fe[1]) * wv0[i0e[1]] + fe[1] * wv0[i0e[1] + 1];
            res.z = (1.0f - fe[2]) * wv0[i0e[2]] + fe[2] * wv0[i0e[2] + 1];
            res.w = (1.0f - fe[3]) * wv0[i0e[3]] + fe[3] * wv0[i0e[3] + 1];
            __builtin_nontemporal_store(res, optr + ni * 2048);        // 1 KB/wave
        }
        {
            f32x4 res;
            res.x = (1.0f - fe[0]) * wv1[i0e[0]] + fe[0] * wv1[i0e[0] + 1];
            res.y = (1.0f - fe[1]) * wv1[i0e[1]] + fe[1] * wv1[i0e[1] + 1];
            res.z = (1.0f - fe[2]) * wv1[i0e[2]] + fe[2] * wv1[i0e[2] + 1];
            res.w = (1.0f - fe[3]) * wv1[i0e[3]] + fe[3] * wv1[i0e[3] + 1];
            __builtin_nontemporal_store(res, optr + ni * 2048 + 1024); // 1 KB/wave
        }
    }

    // ---- bilinear tail: 784 out1 elements per block, overlaps store drain ----
    if (tid < BILIN_PER_BLOCK) {
        int idx = o * BILIN_PER_BLOCK + tid;
        int pix = idx % 49;                    // ky*7 + kx
        int no  = (idx / 49) & 15;
        int oo  = idx / (49 * 16);

        float gx = grid_Rn[pix * 2 + 0];
        float gy = grid_Rn[pix * 2 + 1];

        float ang = -out_H[no];
        float sn, cs;
        sincosf(ang, &sn, &cs);

        float x = cs * gx - sn * gy;
        float y = sn * gx + cs * gy;

        float X = (x + 1.0f) * 3.0f;           // align_corners map to [0,6]
        float Y = (y + 1.0f) * 3.0f;

        float x0f = floorf(X), y0f = floorf(Y);
        float wx = X - x0f,    wy = Y - y0f;
        int   x0 = (int)x0f,   y0 = (int)y0f;

        const float* img = weight + oo * 49;

        auto gat = [&](int yy, int xx) -> float {
            bool v = (yy >= 0) & (yy < 7) & (xx >= 0) & (xx < 7);
            int yc = min(max(yy, 0), 6);
            int xc = min(max(xx, 0), 6);
            float val = img[yc * 7 + xc];
            return v ? val : 0.0f;
        };

        float r = (1.0f - wy) * (1.0f - wx) * gat(y0,     x0)
                + (1.0f - wy) * wx          * gat(y0,     x0 + 1)
                + wy          * (1.0f - wx) * gat(y0 + 1, x0)
                + wy          * wx          * gat(y0 + 1, x0 + 1);

        out1[idx] = mask[pix] * r;
    }
}

extern "C" void kernel_launch(void* const* d_in, const int* in_sizes, int n_in,
                              void* d_out, int out_size, void* d_ws, size_t ws_size,
                              hipStream_t stream) {
    const float* in_H     = (const float*)d_in[0];
    const float* out_H    = (const float*)d_in[1];
    const float* weight_H = (const float*)d_in[2];
    const float* weight   = (const float*)d_in[3];
    // d_in[4] = grid_H (implicit in uniform-grid formula), unused
    const float* grid_Rn  = (const float*)d_in[5];
    const float* mask     = (const float*)d_in[6];

    float* out0 = (float*)d_out;
    float* out1 = out0 + OUT0_SIZE;

    hipLaunchKernelGGL(fused_kernel, dim3(C_O), dim3(1024), 0, stream,
                       in_H, out_H, weight_H, weight, grid_Rn, mask, out0, out1);
}

// Round 6
// 54.966 us; speedup vs baseline: 1.0741x; 1.0470x over previous
//
#include <hip/hip_runtime.h>

#define TWO_PI_F 6.283185307179586f

// Problem constants (from setup_inputs)
#define C_O   512
#define C_CIN 512
#define C_K   16
#define C_KS  7
#define C_NI  16
#define C_NO  16

#define OUT0_SIZE (C_O * C_NI * C_CIN * C_NO)   // 67,108,864
#define OUT1_SIZE (C_O * C_NO * C_KS * C_KS)    // 401,408

// LDS row stride: 16 data + 1 wrap-dup + 1 pad = 18 floats. 18c mod 32 spreads
// 16 consecutive rows over 16 distinct banks; 8B-aligned for float2 staging.
#define SW_STRIDE 18

#define BILIN_BLOCKS  392    // OUT1_SIZE / 1024 exactly
#define INTERP_BLOCKS 2048   // C_O * 4  (4 ni per block)

typedef float f32x4 __attribute__((ext_vector_type(4)));

// ---------------------------------------------------------------------------
// Fused kernel (round-3 structure, REGULAR stores: let Infinity Cache absorb
// the 262 MB write stream — out0 fits in the 256 MB L3).
// Blocks [0, 392): bilinear sampling (out1).
// Blocks [392, 392+2048): circular-lerp broadcast (out0), one block per
// (o, ni-group-of-4). 1024 threads; 2 blocks/CU -> 32 waves/CU.
// ---------------------------------------------------------------------------
__global__ __launch_bounds__(1024) void fused_kernel(
    const float* __restrict__ in_H,
    const float* __restrict__ out_H,
    const float* __restrict__ weight_H,
    const float* __restrict__ weight,
    const float* __restrict__ grid_Rn,
    const float* __restrict__ mask,
    float* __restrict__ out0,
    float* __restrict__ out1)
{
    __shared__ float s_w[C_CIN * SW_STRIDE];   // 36,864 B
    __shared__ float s_t[64];

    const int tid = threadIdx.x;
    const int bid = blockIdx.x;

    if (bid < BILIN_BLOCKS) {
        // ---- bilinear branch: out1[o,no,0,ky,kx] ----
        int idx = bid * 1024 + tid;            // < OUT1_SIZE exactly
        int pix = idx % 49;                    // ky*7 + kx
        int no  = (idx / 49) & 15;
        int o   = idx / (49 * 16);

        float gx = grid_Rn[pix * 2 + 0];
        float gy = grid_Rn[pix * 2 + 1];

        float ang = -out_H[no];
        float sn, cs;
        sincosf(ang, &sn, &cs);

        float x = cs * gx - sn * gy;
        float y = sn * gx + cs * gy;

        float X = (x + 1.0f) * 3.0f;           // align_corners map to [0,6]
        float Y = (y + 1.0f) * 3.0f;

        float x0f = floorf(X), y0f = floorf(Y);
        float wx = X - x0f,    wy = Y - y0f;
        int   x0 = (int)x0f,   y0 = (int)y0f;

        const float* img = weight + o * 49;

        auto gat = [&](int yy, int xx) -> float {
            bool v = (yy >= 0) & (yy < 7) & (xx >= 0) & (xx < 7);
            int yc = min(max(yy, 0), 6);
            int xc = min(max(xx, 0), 6);
            float val = img[yc * 7 + xc];
            return v ? val : 0.0f;
        };

        float r = (1.0f - wy) * (1.0f - wx) * gat(y0,     x0)
                + (1.0f - wy) * wx          * gat(y0,     x0 + 1)
                + wy          * (1.0f - wx) * gat(y0 + 1, x0)
                + wy          * wx          * gat(y0 + 1, x0 + 1);

        out1[idx] = mask[pix] * r;
        return;
    }

    // ---- interp branch ----
    const int ibid = bid - BILIN_BLOCKS;
    const int o    = ibid >> 2;
    const int nig  = ibid & 3;                 // ni group: ni = nig*4 + ni_l

    // t coordinate for this block's 4 ni x 16 no
    if (tid < 64) {
        int ni_l = tid >> 4;
        int no   = tid & 15;
        float x = in_H[nig * 4 + ni_l] - out_H[no];
        float r = fmodf(x, TWO_PI_F);
        if (r < 0.0f) r += TWO_PI_F;
        s_t[tid] = r * (16.0f / TWO_PI_F);
    }

    // Stage weight_H[o,:,:] (512 rows x 16 floats = 32 KB), stride 18 + wrap dup
    const float4* wsrc = reinterpret_cast<const float4*>(weight_H) + (size_t)o * 2048;
#pragma unroll
    for (int j = 0; j < 2; ++j) {
        int f = j * 1024 + tid;                // float4 index
        float4 v = wsrc[f];
        int c    = f >> 2;
        int part = f & 3;
        float* row = &s_w[c * SW_STRIDE + part * 4];
        reinterpret_cast<float2*>(row)[0] = make_float2(v.x, v.y);
        reinterpret_cast<float2*>(row)[1] = make_float2(v.z, v.w);
        if (part == 0) s_w[c * SW_STRIDE + 16] = v.x;
    }
    __syncthreads();

    const int q    = tid & 3;                  // no quad: no = q*4 + e
    const int crow = tid >> 2;
    f32x4* obase = reinterpret_cast<f32x4*>(out0)
                 + ((size_t)o << 15) + ((size_t)nig << 13);

#pragma unroll
    for (int it = 0; it < 8; ++it) {
        int ni_l = it >> 1;                    // uniform across wave
        int c    = ((it & 1) << 8) + crow;
        const float* wv = &s_w[c * SW_STRIDE];
        float r0, r1, r2, r3;
        {
            float tt = s_t[ni_l * 16 + q * 4 + 0];
            float fl = floorf(tt); int i0 = ((int)fl) & 15; float fr = tt - fl;
            r0 = (1.0f - fr) * wv[i0] + fr * wv[i0 + 1];
        }
        {
            float tt = s_t[ni_l * 16 + q * 4 + 1];
            float fl = floorf(tt); int i0 = ((int)fl) & 15; float fr = tt - fl;
            r1 = (1.0f - fr) * wv[i0] + fr * wv[i0 + 1];
        }
        {
            float tt = s_t[ni_l * 16 + q * 4 + 2];
            float fl = floorf(tt); int i0 = ((int)fl) & 15; float fr = tt - fl;
            r2 = (1.0f - fr) * wv[i0] + fr * wv[i0 + 1];
        }
        {
            float tt = s_t[ni_l * 16 + q * 4 + 3];
            float fl = floorf(tt); int i0 = ((int)fl) & 15; float fr = tt - fl;
            r3 = (1.0f - fr) * wv[i0] + fr * wv[i0 + 1];
        }
        f32x4 res = {r0, r1, r2, r3};
        obase[it * 1024 + tid] = res;          // regular store: L3-allocating
    }
}

extern "C" void kernel_launch(void* const* d_in, const int* in_sizes, int n_in,
                              void* d_out, int out_size, void* d_ws, size_t ws_size,
                              hipStream_t stream) {
    const float* in_H     = (const float*)d_in[0];
    const float* out_H    = (const float*)d_in[1];
    const float* weight_H = (const float*)d_in[2];
    const float* weight   = (const float*)d_in[3];
    // d_in[4] = grid_H (implicit in uniform-grid formula), unused
    const float* grid_Rn  = (const float*)d_in[5];
    const float* mask     = (const float*)d_in[6];

    float* out0 = (float*)d_out;
    float* out1 = out0 + OUT0_SIZE;

    hipLaunchKernelGGL(fused_kernel, dim3(BILIN_BLOCKS + INTERP_BLOCKS), dim3(1024),
                       0, stream,
                       in_H, out_H, weight_H, weight, grid_Rn, mask, out0, out1);
}